// Round 2
// baseline (671.078 us; speedup 1.0000x reference)
//
#include <hip/hip_runtime.h>
#include <stdint.h>

#define NN 50000
#define EE 800000
#define ET 850000
#define INC 128
#define HID 256
#define OUTC 128

typedef __attribute__((ext_vector_type(4))) float f32x4;
typedef __attribute__((ext_vector_type(8))) short s16x8;
typedef __attribute__((ext_vector_type(4))) short s16x4;

static __device__ __forceinline__ float b2f(unsigned short u){
  union { float f; unsigned int i; } v; v.i = ((unsigned int)u) << 16; return v.f;
}
static __device__ __forceinline__ unsigned short f2b(float f){
  union { float f; unsigned int i; } v; v.f = f;
  unsigned int r = v.i + 0x7FFFu + ((v.i >> 16) & 1u);
  return (unsigned short)(r >> 16);
}

// ---------------- CSR build ----------------
__global__ void k_degree(const int* __restrict__ ei, int* __restrict__ cnt){
  int e = blockIdx.x * 256 + threadIdx.x;
  if (e >= ET) return;
  int d = (e < EE) ? ei[EE + e] : (e - EE);
  atomicAdd(&cnt[d], 1);
}

__global__ void k_scan(const int* __restrict__ deg, int* __restrict__ off){
  const int T = 1024; int tid = threadIdx.x;
  __shared__ int s[1024]; __shared__ int carry_s;
  if (tid == 0) carry_s = 0;
  __syncthreads();
  for (int base = 0; base < NN; base += T){
    int i = base + tid;
    int v = (i < NN) ? deg[i] : 0;
    s[tid] = v; __syncthreads();
    for (int o = 1; o < T; o <<= 1){
      int t = (tid >= o) ? s[tid - o] : 0; __syncthreads();
      s[tid] += t; __syncthreads();
    }
    int carry = carry_s;
    int incl = s[tid];
    if (i < NN) off[i] = carry + incl - v;
    __syncthreads();
    if (tid == T - 1) carry_s = carry + incl;
    __syncthreads();
  }
  if (tid == 0) off[NN] = carry_s;
}

__global__ void k_scatter(const int* __restrict__ ei, const int* __restrict__ off,
                          int* __restrict__ cnt, int* __restrict__ ssrc){
  int e = blockIdx.x * 256 + threadIdx.x;
  if (e >= ET) return;
  int s, d;
  if (e < EE){ s = ei[e]; d = ei[EE + e]; } else { s = e - EE; d = s; }
  int p = off[d] + atomicAdd(&cnt[d], 1);
  ssrc[p] = s;
}

// ---------------- W transpose + f32->bf16 (tiny) ----------------
__global__ void k_transpose(const float* __restrict__ W,
                            unsigned short* __restrict__ WT, int K){
  int idx = blockIdx.x * 256 + threadIdx.x;
  if (idx >= K * HID) return;
  int k = idx >> 8, c = idx & 255;
  WT[c * K + k] = f2b(W[idx]);
}

// ---------------- MFMA GEMM: C[M,256] = A[M,K] @ W[K,256] (WT is [256,K] bf16) ----------------
// AF32: A is float32 (layer 1 input x); else A is bf16 (our intermediates).
template<bool AF32>
__global__ __launch_bounds__(256) void k_gemm(const void* __restrict__ Av,
    const unsigned short* __restrict__ WT, unsigned short* __restrict__ C, int M, int K){
  __shared__ unsigned short sA[64][72];   // +8 shorts pad vs 64: breaks bank aliasing
  __shared__ unsigned short sB[64][72];
  int tid = threadIdx.x;
  int wave = tid >> 6, lane = tid & 63;
  int bm0 = blockIdx.x * 64, bn0 = blockIdx.y * 64;
  int wr0 = (wave >> 1) * 32, wc0 = (wave & 1) * 32;
  f32x4 acc[2][2];
  #pragma unroll
  for (int i = 0; i < 2; i++)
    #pragma unroll
    for (int j = 0; j < 2; j++) acc[i][j] = (f32x4){0.f, 0.f, 0.f, 0.f};

  for (int k0 = 0; k0 < K; k0 += 64){
    #pragma unroll
    for (int i = 0; i < 2; i++){
      int idx = tid + i * 256;            // 0..511 : r=idx>>3 (64 rows), 8 k-elems each
      int r = idx >> 3, kb = (idx & 7) * 8;
      int gr = bm0 + r;
      if constexpr (AF32){
        const float* A = (const float*)Av;
        unsigned short t[8] = {0,0,0,0,0,0,0,0};
        if (gr < M){
          const float4* p = (const float4*)(A + (size_t)gr * K + k0 + kb);
          float4 v0 = p[0], v1 = p[1];
          t[0]=f2b(v0.x); t[1]=f2b(v0.y); t[2]=f2b(v0.z); t[3]=f2b(v0.w);
          t[4]=f2b(v1.x); t[5]=f2b(v1.y); t[6]=f2b(v1.z); t[7]=f2b(v1.w);
        }
        *(s16x8*)&sA[r][kb] = *(s16x8*)t;
      } else {
        const unsigned short* A = (const unsigned short*)Av;
        s16x8 v = (s16x8){0,0,0,0,0,0,0,0};
        if (gr < M) v = *(const s16x8*)(A + (size_t)gr * K + k0 + kb);
        *(s16x8*)&sA[r][kb] = v;
      }
      s16x8 wv = *(const s16x8*)(WT + (size_t)(bn0 + r) * K + k0 + kb);
      *(s16x8*)&sB[r][kb] = wv;
    }
    __syncthreads();
    #pragma unroll
    for (int kk = 0; kk < 64; kk += 32){
      int kl = kk + (lane >> 4) * 8;
      s16x8 a0 = *(const s16x8*)&sA[wr0 + (lane & 15)][kl];
      s16x8 a1 = *(const s16x8*)&sA[wr0 + 16 + (lane & 15)][kl];
      s16x8 b0 = *(const s16x8*)&sB[wc0 + (lane & 15)][kl];
      s16x8 b1 = *(const s16x8*)&sB[wc0 + 16 + (lane & 15)][kl];
      acc[0][0] = __builtin_amdgcn_mfma_f32_16x16x32_bf16(a0, b0, acc[0][0], 0, 0, 0);
      acc[0][1] = __builtin_amdgcn_mfma_f32_16x16x32_bf16(a0, b1, acc[0][1], 0, 0, 0);
      acc[1][0] = __builtin_amdgcn_mfma_f32_16x16x32_bf16(a1, b0, acc[1][0], 0, 0, 0);
      acc[1][1] = __builtin_amdgcn_mfma_f32_16x16x32_bf16(a1, b1, acc[1][1], 0, 0, 0);
    }
    __syncthreads();
  }
  // D layout: col = lane&15, row = (lane>>4)*4 + r   [measured m89/m91]
  #pragma unroll
  for (int mi = 0; mi < 2; mi++){
    #pragma unroll
    for (int ni = 0; ni < 2; ni++){
      int col = bn0 + wc0 + ni * 16 + (lane & 15);
      int rb = bm0 + wr0 + mi * 16 + (lane >> 4) * 4;
      #pragma unroll
      for (int r = 0; r < 4; r++){
        int row = rb + r;
        if (row < M) C[(size_t)row * HID + col] = f2b(acc[mi][ni][r]);
      }
    }
  }
}

// ---------------- per-node attention halves (h bf16, a_* f32) ----------------
__global__ __launch_bounds__(256) void k_alpha(const unsigned short* __restrict__ h,
    const float* __restrict__ a_src, const float* __restrict__ a_dst,
    float* __restrict__ as_, float* __restrict__ ad_){
  int gid = blockIdx.x * 256 + threadIdx.x;
  int wid = gid >> 6, lane = gid & 63;
  if (wid >= NN) return;
  s16x4 hv = *(const s16x4*)(h + (size_t)wid * HID + lane * 4);
  float4 sv = *(const float4*)(a_src + lane * 4);
  float4 dv = *(const float4*)(a_dst + lane * 4);
  float ps = 0.f, pd = 0.f;
  float x0 = b2f((unsigned short)hv[0]), x1 = b2f((unsigned short)hv[1]);
  float x2 = b2f((unsigned short)hv[2]), x3 = b2f((unsigned short)hv[3]);
  ps = x0*sv.x + x1*sv.y + x2*sv.z + x3*sv.w;
  pd = x0*dv.x + x1*dv.y + x2*dv.z + x3*dv.w;
  #pragma unroll
  for (int m = 1; m < 16; m <<= 1){ ps += __shfl_xor(ps, m, 64); pd += __shfl_xor(pd, m, 64); }
  if ((lane & 15) == 0){
    as_[wid * 4 + (lane >> 4)] = ps;
    ad_[wid * 4 + (lane >> 4)] = pd;
  }
}

// ---------------- softmax-weighted aggregation (one wave per dst node) ----------------
__global__ __launch_bounds__(256) void k_aggregate(const int* __restrict__ off,
    const int* __restrict__ ssrc, const float* __restrict__ as_, const float* __restrict__ ad_,
    const unsigned short* __restrict__ h, const float* __restrict__ bias,
    unsigned short* __restrict__ out){
  int gid = blockIdx.x * 256 + threadIdx.x;
  int wid = gid >> 6, lane = gid & 63;
  if (wid >= NN) return;
  int start = off[wid], end = off[wid + 1], deg = end - start;

  // phase 1: online softmax stats. lane -> edge j = lane>>2, head = lane&3
  int hh = lane & 3;
  float ad1 = ad_[wid * 4 + hh];
  float pm = -1e30f, ps = 0.f;
  for (int base = 0; base < deg; base += 16){
    int j = base + (lane >> 2);
    if (j < deg){
      int s = ssrc[start + j];
      float lg = as_[s * 4 + hh] + ad1;
      lg = lg > 0.f ? lg : 0.2f * lg;            // leaky_relu(0.2)
      float nm = fmaxf(pm, lg);
      ps = ps * __expf(pm - nm) + __expf(lg - nm);
      pm = nm;
    }
  }
  #pragma unroll
  for (int m = 4; m < 64; m <<= 1){
    float om = __shfl_xor(pm, m, 64), os = __shfl_xor(ps, m, 64);
    float nm = fmaxf(pm, om);
    ps = ps * __expf(pm - nm) + os * __expf(om - nm);
    pm = nm;
  }
  // lane&3==k holds (m,sum) for head k; redistribute to head = lane>>4
  int h2 = lane >> 4;
  float m_h = __shfl(pm, h2, 64);
  float inv = 1.f / (__shfl(ps, h2, 64) + 1e-16f);

  // phase 2: accumulate messages. lane -> channels 4*lane..4*lane+3, head = lane>>4
  float ad2 = ad_[wid * 4 + h2];
  float a0 = 0.f, a1 = 0.f, a2 = 0.f, a3 = 0.f;
  for (int p = start; p < end; p++){
    int s = ssrc[p];
    float lg = as_[s * 4 + h2] + ad2;
    lg = lg > 0.f ? lg : 0.2f * lg;
    float wgt = __expf(lg - m_h) * inv;
    s16x4 hv = *(const s16x4*)(h + (size_t)s * HID + lane * 4);
    a0 += wgt * b2f((unsigned short)hv[0]);
    a1 += wgt * b2f((unsigned short)hv[1]);
    a2 += wgt * b2f((unsigned short)hv[2]);
    a3 += wgt * b2f((unsigned short)hv[3]);
  }
  float4 bv = *(const float4*)(bias + lane * 4);
  float o_[4] = {a0 + bv.x, a1 + bv.y, a2 + bv.z, a3 + bv.w};
  size_t ob = (size_t)wid * HID + lane * 4;
  #pragma unroll
  for (int j = 0; j < 4; j++){
    float v = o_[j];
    v = v > 0.f ? v : (__expf(v) - 1.f);         // elu
    out[ob + j] = f2b(v);
  }
}

// ---------------- mean pool + head ----------------
__global__ void k_pool(const unsigned short* __restrict__ X, float* __restrict__ pool){
  int c = threadIdx.x;             // 256
  float acc = 0.f;
  for (int n = blockIdx.x; n < NN; n += gridDim.x) acc += b2f(X[(size_t)n * HID + c]);
  atomicAdd(&pool[c], acc);
}

__global__ void k_head(const float* __restrict__ pool, const float* __restrict__ hW,
                       const float* __restrict__ hb, float* __restrict__ outp){
  int o = threadIdx.x;             // 128
  float acc = hb[o];
  const float invN = 1.f / (float)NN;
  for (int c = 0; c < HID; c++) acc += pool[c] * invN * hW[c * OUTC + o];
  outp[o] = acc;
}

extern "C" void kernel_launch(void* const* d_in, const int* in_sizes, int n_in,
                              void* d_out, int out_size, void* d_ws, size_t ws_size,
                              hipStream_t stream){
  const float* x  = (const float*)d_in[0];
  const int* ei   = (const int*)d_in[1];
  const float* W[3]   = {(const float*)d_in[2],  (const float*)d_in[6],  (const float*)d_in[10]};
  const float* Asr[3] = {(const float*)d_in[3],  (const float*)d_in[7],  (const float*)d_in[11]};
  const float* Adt[3] = {(const float*)d_in[4],  (const float*)d_in[8],  (const float*)d_in[12]};
  const float* B[3]   = {(const float*)d_in[5],  (const float*)d_in[9],  (const float*)d_in[13]};
  const float* hW = (const float*)d_in[14];
  const float* hb = (const float*)d_in[15];

  char* w = (char*)d_ws; size_t o = 0;
  auto alloc = [&](size_t b) -> void* { void* p = w + o; o = (o + b + 255) & ~(size_t)255; return p; };
  int* cnt  = (int*)alloc((size_t)NN * 4);
  int* off  = (int*)alloc((size_t)(NN + 1) * 4);
  int* ssrc = (int*)alloc((size_t)ET * 4);
  unsigned short* hbuf = (unsigned short*)alloc((size_t)NN * HID * 2);
  float* as_ = (float*)alloc((size_t)NN * 4 * 4);
  float* ad_ = (float*)alloc((size_t)NN * 4 * 4);
  unsigned short* X0 = (unsigned short*)alloc((size_t)NN * HID * 2);
  unsigned short* X1 = (unsigned short*)alloc((size_t)NN * HID * 2);
  unsigned short* WT = (unsigned short*)alloc((size_t)256 * 256 * 2);
  float* pool = (float*)alloc(256 * 4);

  hipMemsetAsync(cnt, 0, (size_t)NN * 4, stream);
  hipMemsetAsync(pool, 0, 256 * 4, stream);
  k_degree<<<(ET + 255) / 256, 256, 0, stream>>>(ei, cnt);
  k_scan<<<1, 1024, 0, stream>>>(cnt, off);
  hipMemsetAsync(cnt, 0, (size_t)NN * 4, stream);
  k_scatter<<<(ET + 255) / 256, 256, 0, stream>>>(ei, off, cnt, ssrc);

  unsigned short* outbuf[3] = {X0, X1, X0};
  int Ks[3] = {INC, HID, HID};
  const void* Ain = (const void*)x;
  for (int l = 0; l < 3; l++){
    int K = Ks[l];
    k_transpose<<<(K * HID + 255) / 256, 256, 0, stream>>>(W[l], WT, K);
    dim3 g((NN + 63) / 64, 4);
    if (l == 0) k_gemm<true ><<<g, 256, 0, stream>>>(Ain, WT, hbuf, NN, K);
    else        k_gemm<false><<<g, 256, 0, stream>>>(Ain, WT, hbuf, NN, K);
    k_alpha<<<(NN * 64 + 255) / 256, 256, 0, stream>>>(hbuf, Asr[l], Adt[l], as_, ad_);
    k_aggregate<<<(NN * 64 + 255) / 256, 256, 0, stream>>>(off, ssrc, as_, ad_, hbuf, B[l], outbuf[l]);
    Ain = (const void*)outbuf[l];
  }
  k_pool<<<256, 256, 0, stream>>>(X0, pool);
  k_head<<<1, 128, 0, stream>>>(pool, hW, hb, (float*)d_out);
}

// Round 3
// 632.559 us; speedup vs baseline: 1.0609x; 1.0609x over previous
//
#include <hip/hip_runtime.h>
#include <stdint.h>

#define NN 50000
#define EE 800000
#define ET 850000
#define INC 128
#define HID 256
#define OUTC 128

typedef __attribute__((ext_vector_type(4))) float f32x4;
typedef __attribute__((ext_vector_type(8))) short s16x8;
typedef __attribute__((ext_vector_type(4))) short s16x4;

static __device__ __forceinline__ float b2f(unsigned short u){
  union { float f; unsigned int i; } v; v.i = ((unsigned int)u) << 16; return v.f;
}
static __device__ __forceinline__ unsigned short f2b(float f){
  union { float f; unsigned int i; } v; v.f = f;
  unsigned int r = v.i + 0x7FFFu + ((v.i >> 16) & 1u);
  return (unsigned short)(r >> 16);
}

// ---------------- CSR build ----------------
__global__ void k_degree(const int* __restrict__ ei, int* __restrict__ cnt){
  int e = blockIdx.x * 256 + threadIdx.x;
  if (e >= ET) return;
  int d = (e < EE) ? ei[EE + e] : (e - EE);
  atomicAdd(&cnt[d], 1);
}

__global__ void k_scan(const int* __restrict__ deg, int* __restrict__ off){
  const int T = 1024; int tid = threadIdx.x;
  __shared__ int s[1024]; __shared__ int carry_s;
  if (tid == 0) carry_s = 0;
  __syncthreads();
  for (int base = 0; base < NN; base += T){
    int i = base + tid;
    int v = (i < NN) ? deg[i] : 0;
    s[tid] = v; __syncthreads();
    for (int o = 1; o < T; o <<= 1){
      int t = (tid >= o) ? s[tid - o] : 0; __syncthreads();
      s[tid] += t; __syncthreads();
    }
    int carry = carry_s;
    int incl = s[tid];
    if (i < NN) off[i] = carry + incl - v;
    __syncthreads();
    if (tid == T - 1) carry_s = carry + incl;
    __syncthreads();
  }
  if (tid == 0) off[NN] = carry_s;
}

__global__ void k_scatter(const int* __restrict__ ei, const int* __restrict__ off,
                          int* __restrict__ cnt, int* __restrict__ ssrc){
  int e = blockIdx.x * 256 + threadIdx.x;
  if (e >= ET) return;
  int s, d;
  if (e < EE){ s = ei[e]; d = ei[EE + e]; } else { s = e - EE; d = s; }
  int p = off[d] + atomicAdd(&cnt[d], 1);
  ssrc[p] = s;
}

// ---------------- W transpose + f32->bf16 (tiny) ----------------
__global__ void k_transpose(const float* __restrict__ W,
                            unsigned short* __restrict__ WT, int K){
  int idx = blockIdx.x * 256 + threadIdx.x;
  if (idx >= K * HID) return;
  int k = idx >> 8, c = idx & 255;
  WT[c * K + k] = f2b(W[idx]);
}

// ---------------- fused MFMA GEMM (64 x 256 tile) + alpha epilogue ----------------
// C[M,256] = A[M,K] @ W[K,256]; WT is [256,K] bf16. 4 waves: wave w owns cols [64w,64w+64).
// Epilogue: wave w computes alpha_s/alpha_d for head w, all 64 rows, from the C tile in LDS.
template<bool AF32>
__global__ __launch_bounds__(256) void k_gemm_fused(const void* __restrict__ Av,
    const unsigned short* __restrict__ WT,
    const float* __restrict__ a_src, const float* __restrict__ a_dst,
    unsigned short* __restrict__ C, float* __restrict__ as_, float* __restrict__ ad_,
    int M, int K){
  __shared__ unsigned short sA[64][72];     // 9216 B
  __shared__ unsigned short sB[256][72];    // 36864 B; reused as sC[64][258] (33024 B)
  int tid = threadIdx.x;
  int wave = tid >> 6, lane = tid & 63;
  int bm0 = blockIdx.x * 64;
  int wc0 = wave * 64;
  f32x4 acc[4][4];
  #pragma unroll
  for (int i = 0; i < 4; i++)
    #pragma unroll
    for (int j = 0; j < 4; j++) acc[i][j] = (f32x4){0.f, 0.f, 0.f, 0.f};

  for (int k0 = 0; k0 < K; k0 += 64){
    // stage A tile: 64 rows x 64 k
    #pragma unroll
    for (int i = 0; i < 2; i++){
      int idx = tid + i * 256;              // 0..511
      int r = idx >> 3, kb = (idx & 7) * 8;
      int gr = bm0 + r;
      if constexpr (AF32){
        const float* A = (const float*)Av;
        unsigned short t[8] = {0,0,0,0,0,0,0,0};
        if (gr < M){
          const float4* p = (const float4*)(A + (size_t)gr * K + k0 + kb);
          float4 v0 = p[0], v1 = p[1];
          t[0]=f2b(v0.x); t[1]=f2b(v0.y); t[2]=f2b(v0.z); t[3]=f2b(v0.w);
          t[4]=f2b(v1.x); t[5]=f2b(v1.y); t[6]=f2b(v1.z); t[7]=f2b(v1.w);
        }
        *(s16x8*)&sA[r][kb] = *(s16x8*)t;
      } else {
        const unsigned short* A = (const unsigned short*)Av;
        s16x8 v = (s16x8){0,0,0,0,0,0,0,0};
        if (gr < M) v = *(const s16x8*)(A + (size_t)gr * K + k0 + kb);
        *(s16x8*)&sA[r][kb] = v;
      }
    }
    // stage B tile: all 256 cols x 64 k
    #pragma unroll
    for (int i = 0; i < 8; i++){
      int idx = tid + i * 256;              // 0..2047
      int r = idx >> 3, kb = (idx & 7) * 8;
      *(s16x8*)&sB[r][kb] = *(const s16x8*)(WT + (size_t)r * K + k0 + kb);
    }
    __syncthreads();
    #pragma unroll
    for (int kk = 0; kk < 64; kk += 32){
      int kl = kk + (lane >> 4) * 8;
      s16x8 af[4], bf[4];
      #pragma unroll
      for (int mi = 0; mi < 4; mi++) af[mi] = *(const s16x8*)&sA[mi * 16 + (lane & 15)][kl];
      #pragma unroll
      for (int ni = 0; ni < 4; ni++) bf[ni] = *(const s16x8*)&sB[wc0 + ni * 16 + (lane & 15)][kl];
      #pragma unroll
      for (int mi = 0; mi < 4; mi++)
        #pragma unroll
        for (int ni = 0; ni < 4; ni++)
          acc[mi][ni] = __builtin_amdgcn_mfma_f32_16x16x32_bf16(af[mi], bf[ni], acc[mi][ni], 0, 0, 0);
    }
    __syncthreads();
  }

  // write C tile to global + LDS (sC), then alpha epilogue
  unsigned short (*sC)[258] = (unsigned short (*)[258])&sB[0][0];
  #pragma unroll
  for (int mi = 0; mi < 4; mi++){
    #pragma unroll
    for (int ni = 0; ni < 4; ni++){
      int col = wc0 + ni * 16 + (lane & 15);
      int rb = mi * 16 + (lane >> 4) * 4;
      #pragma unroll
      for (int r = 0; r < 4; r++){
        int row = rb + r;
        unsigned short us = f2b(acc[mi][ni][r]);
        sC[row][col] = us;
        if (bm0 + row < M) C[(size_t)(bm0 + row) * HID + col] = us;
      }
    }
  }
  __syncthreads();
  // wave w -> head q=w; lane -> row. dot 64 channels with a_src/a_dst.
  {
    int q = wave, r = lane;
    float ps = 0.f, pd = 0.f;
    #pragma unroll 8
    for (int d = 0; d < 64; d++){
      float hv = b2f(sC[r][q * 64 + d]);
      ps += hv * a_src[q * 64 + d];
      pd += hv * a_dst[q * 64 + d];
    }
    if (bm0 + r < M){
      as_[(size_t)(bm0 + r) * 4 + q] = ps;
      ad_[(size_t)(bm0 + r) * 4 + q] = pd;
    }
  }
}

// ---------------- online softmax aggregation (one wave per dst node, single pass) ----------------
__global__ __launch_bounds__(256) void k_aggregate(const int* __restrict__ off,
    const int* __restrict__ ssrc, const float* __restrict__ as_, const float* __restrict__ ad_,
    const unsigned short* __restrict__ h, const float* __restrict__ bias,
    unsigned short* __restrict__ out){
  int gid = blockIdx.x * 256 + threadIdx.x;
  int wid = gid >> 6, lane = gid & 63;
  if (wid >= NN) return;
  int start = off[wid], end = off[wid + 1];
  int h2 = lane >> 4;                        // head owned by this lane
  float ad2 = ad_[(size_t)wid * 4 + h2];
  float m = -1e30f, ssum = 0.f;
  float a0 = 0.f, a1 = 0.f, a2 = 0.f, a3 = 0.f;
  for (int p = start; p < end; p++){
    int s = ssrc[p];
    float lg = as_[(size_t)s * 4 + h2] + ad2;
    lg = lg > 0.f ? lg : 0.2f * lg;          // leaky_relu(0.2)
    float nm = fmaxf(m, lg);
    float f = __expf(m - nm);                // rescale (==1 when max unchanged)
    float w = __expf(lg - nm);
    m = nm;
    ssum = ssum * f + w;
    s16x4 hv = *(const s16x4*)(h + (size_t)s * HID + lane * 4);
    a0 = a0 * f + w * b2f((unsigned short)hv[0]);
    a1 = a1 * f + w * b2f((unsigned short)hv[1]);
    a2 = a2 * f + w * b2f((unsigned short)hv[2]);
    a3 = a3 * f + w * b2f((unsigned short)hv[3]);
  }
  float inv = 1.f / (ssum + 1e-16f);
  float4 bv = *(const float4*)(bias + lane * 4);
  float o_[4] = {a0 * inv + bv.x, a1 * inv + bv.y, a2 * inv + bv.z, a3 * inv + bv.w};
  size_t ob = (size_t)wid * HID + lane * 4;
  #pragma unroll
  for (int j = 0; j < 4; j++){
    float v = o_[j];
    v = v > 0.f ? v : (__expf(v) - 1.f);     // elu
    out[ob + j] = f2b(v);
  }
}

// ---------------- mean pool + head ----------------
__global__ void k_pool(const unsigned short* __restrict__ X, float* __restrict__ pool){
  int c = threadIdx.x;             // 256
  float acc = 0.f;
  for (int n = blockIdx.x; n < NN; n += gridDim.x) acc += b2f(X[(size_t)n * HID + c]);
  atomicAdd(&pool[c], acc);
}

__global__ void k_head(const float* __restrict__ pool, const float* __restrict__ hW,
                       const float* __restrict__ hb, float* __restrict__ outp){
  int o = threadIdx.x;             // 128
  float acc = hb[o];
  const float invN = 1.f / (float)NN;
  for (int c = 0; c < HID; c++) acc += pool[c] * invN * hW[c * OUTC + o];
  outp[o] = acc;
}

extern "C" void kernel_launch(void* const* d_in, const int* in_sizes, int n_in,
                              void* d_out, int out_size, void* d_ws, size_t ws_size,
                              hipStream_t stream){
  const float* x  = (const float*)d_in[0];
  const int* ei   = (const int*)d_in[1];
  const float* W[3]   = {(const float*)d_in[2],  (const float*)d_in[6],  (const float*)d_in[10]};
  const float* Asr[3] = {(const float*)d_in[3],  (const float*)d_in[7],  (const float*)d_in[11]};
  const float* Adt[3] = {(const float*)d_in[4],  (const float*)d_in[8],  (const float*)d_in[12]};
  const float* B[3]   = {(const float*)d_in[5],  (const float*)d_in[9],  (const float*)d_in[13]};
  const float* hW = (const float*)d_in[14];
  const float* hb = (const float*)d_in[15];

  char* w = (char*)d_ws; size_t o = 0;
  auto alloc = [&](size_t b) -> void* { void* p = w + o; o = (o + b + 255) & ~(size_t)255; return p; };
  int* cnt  = (int*)alloc((size_t)NN * 4);
  int* off  = (int*)alloc((size_t)(NN + 1) * 4);
  int* ssrc = (int*)alloc((size_t)ET * 4);
  unsigned short* hbuf = (unsigned short*)alloc((size_t)NN * HID * 2);
  float* as_ = (float*)alloc((size_t)NN * 4 * 4);
  float* ad_ = (float*)alloc((size_t)NN * 4 * 4);
  unsigned short* X0 = (unsigned short*)alloc((size_t)NN * HID * 2);
  unsigned short* X1 = (unsigned short*)alloc((size_t)NN * HID * 2);
  unsigned short* WT = (unsigned short*)alloc((size_t)256 * 256 * 2);
  float* pool = (float*)alloc(256 * 4);

  hipMemsetAsync(cnt, 0, (size_t)NN * 4, stream);
  hipMemsetAsync(pool, 0, 256 * 4, stream);
  k_degree<<<(ET + 255) / 256, 256, 0, stream>>>(ei, cnt);
  k_scan<<<1, 1024, 0, stream>>>(cnt, off);
  hipMemsetAsync(cnt, 0, (size_t)NN * 4, stream);
  k_scatter<<<(ET + 255) / 256, 256, 0, stream>>>(ei, off, cnt, ssrc);

  unsigned short* outbuf[3] = {X0, X1, X0};
  int Ks[3] = {INC, HID, HID};
  const void* Ain = (const void*)x;
  int gB = (NN + 63) / 64;
  for (int l = 0; l < 3; l++){
    int K = Ks[l];
    k_transpose<<<(K * HID + 255) / 256, 256, 0, stream>>>(W[l], WT, K);
    if (l == 0) k_gemm_fused<true ><<<gB, 256, 0, stream>>>(Ain, WT, Asr[l], Adt[l], hbuf, as_, ad_, NN, K);
    else        k_gemm_fused<false><<<gB, 256, 0, stream>>>(Ain, WT, Asr[l], Adt[l], hbuf, as_, ad_, NN, K);
    k_aggregate<<<(NN * 64 + 255) / 256, 256, 0, stream>>>(off, ssrc, as_, ad_, hbuf, B[l], outbuf[l]);
    Ain = (const void*)outbuf[l];
  }
  k_pool<<<256, 256, 0, stream>>>(X0, pool);
  k_head<<<1, 128, 0, stream>>>(pool, hW, hb, (float*)d_out);
}

// Round 4
// 560.357 us; speedup vs baseline: 1.1976x; 1.1288x over previous
//
#include <hip/hip_runtime.h>
#include <stdint.h>

#define NN 50000
#define EE 800000
#define ET 850000
#define INC 128
#define HID 256
#define OUTC 128

typedef __attribute__((ext_vector_type(4))) float f32x4;
typedef __attribute__((ext_vector_type(8))) short s16x8;
typedef __attribute__((ext_vector_type(4))) short s16x4;

static __device__ __forceinline__ float b2f(unsigned short u){
  union { float f; unsigned int i; } v; v.i = ((unsigned int)u) << 16; return v.f;
}
static __device__ __forceinline__ unsigned short f2b(float f){
  union { float f; unsigned int i; } v; v.f = f;
  unsigned int r = v.i + 0x7FFFu + ((v.i >> 16) & 1u);
  return (unsigned short)(r >> 16);
}

// ---------------- CSR build ----------------
__global__ void k_degree(const int* __restrict__ ei, int* __restrict__ cnt){
  int e = blockIdx.x * 256 + threadIdx.x;
  if (e >= ET) return;
  int d = (e < EE) ? ei[EE + e] : (e - EE);
  atomicAdd(&cnt[d], 1);
}

__global__ void k_scan(const int* __restrict__ deg, int* __restrict__ off){
  const int T = 1024; int tid = threadIdx.x;
  __shared__ int s[1024]; __shared__ int carry_s;
  if (tid == 0) carry_s = 0;
  __syncthreads();
  for (int base = 0; base < NN; base += T){
    int i = base + tid;
    int v = (i < NN) ? deg[i] : 0;
    s[tid] = v; __syncthreads();
    for (int o = 1; o < T; o <<= 1){
      int t = (tid >= o) ? s[tid - o] : 0; __syncthreads();
      s[tid] += t; __syncthreads();
    }
    int carry = carry_s;
    int incl = s[tid];
    if (i < NN) off[i] = carry + incl - v;
    __syncthreads();
    if (tid == T - 1) carry_s = carry + incl;
    __syncthreads();
  }
  if (tid == 0) off[NN] = carry_s;
}

__global__ void k_scatter(const int* __restrict__ ei, const int* __restrict__ off,
                          int* __restrict__ cnt, int* __restrict__ ssrc){
  int e = blockIdx.x * 256 + threadIdx.x;
  if (e >= ET) return;
  int s, d;
  if (e < EE){ s = ei[e]; d = ei[EE + e]; } else { s = e - EE; d = s; }
  int p = off[d] + atomicAdd(&cnt[d], 1);
  ssrc[p] = s;
}

// ---------------- W transpose + f32->bf16 (tiny) ----------------
__global__ void k_transpose(const float* __restrict__ W,
                            unsigned short* __restrict__ WT, int K){
  int idx = blockIdx.x * 256 + threadIdx.x;
  if (idx >= K * HID) return;
  int k = idx >> 8, c = idx & 255;
  WT[c * K + k] = f2b(W[idx]);
}

// ---------------- fused MFMA GEMM (64 x 256 tile) + alpha epilogue ----------------
// C[M,256] = A[M,K] @ W[K,256]; WT is [256,K] bf16, L2-resident (128KB max):
// B fragments are read directly from global (no LDS staging). sA unioned with
// epilogue sC. 4 waves: wave w owns cols [64w, 64w+64).
template<bool AF32>
__global__ __launch_bounds__(256) void k_gemm_fused(const void* __restrict__ Av,
    const unsigned short* __restrict__ WT,
    const float* __restrict__ a_src, const float* __restrict__ a_dst,
    unsigned short* __restrict__ C, float* __restrict__ as_, float* __restrict__ ad_,
    int M, int K){
  __shared__ unsigned short sMem[64 * 258];              // 33024 B
  unsigned short (*sA)[72]  = (unsigned short (*)[72])sMem;
  unsigned short (*sC)[258] = (unsigned short (*)[258])sMem;
  int tid = threadIdx.x;
  int wave = tid >> 6, lane = tid & 63;
  int bm0 = blockIdx.x * 64;
  int wc0 = wave * 64;
  f32x4 acc[4][4];
  #pragma unroll
  for (int i = 0; i < 4; i++)
    #pragma unroll
    for (int j = 0; j < 4; j++) acc[i][j] = (f32x4){0.f, 0.f, 0.f, 0.f};

  for (int k0 = 0; k0 < K; k0 += 64){
    // stage A tile: 64 rows x 64 k (512 chunks of 8 bf16)
    #pragma unroll
    for (int i = 0; i < 2; i++){
      int idx = tid + i * 256;
      int r = idx >> 3, kb = (idx & 7) * 8;
      int gr = bm0 + r;
      if constexpr (AF32){
        const float* A = (const float*)Av;
        unsigned short t[8] = {0,0,0,0,0,0,0,0};
        if (gr < M){
          const float4* p = (const float4*)(A + (size_t)gr * K + k0 + kb);
          float4 v0 = p[0], v1 = p[1];
          t[0]=f2b(v0.x); t[1]=f2b(v0.y); t[2]=f2b(v0.z); t[3]=f2b(v0.w);
          t[4]=f2b(v1.x); t[5]=f2b(v1.y); t[6]=f2b(v1.z); t[7]=f2b(v1.w);
        }
        *(s16x8*)&sA[r][kb] = *(s16x8*)t;
      } else {
        const unsigned short* A = (const unsigned short*)Av;
        s16x8 v = (s16x8){0,0,0,0,0,0,0,0};
        if (gr < M) v = *(const s16x8*)(A + (size_t)gr * K + k0 + kb);
        *(s16x8*)&sA[r][kb] = v;
      }
    }
    __syncthreads();
    #pragma unroll
    for (int kk = 0; kk < 64; kk += 32){
      int kl = kk + (lane >> 4) * 8;
      s16x8 af[4], bf[4];
      #pragma unroll
      for (int ni = 0; ni < 4; ni++)
        bf[ni] = *(const s16x8*)(WT + (size_t)(wc0 + ni * 16 + (lane & 15)) * K + k0 + kl);
      #pragma unroll
      for (int mi = 0; mi < 4; mi++) af[mi] = *(const s16x8*)&sA[mi * 16 + (lane & 15)][kl];
      #pragma unroll
      for (int mi = 0; mi < 4; mi++)
        #pragma unroll
        for (int ni = 0; ni < 4; ni++)
          acc[mi][ni] = __builtin_amdgcn_mfma_f32_16x16x32_bf16(af[mi], bf[ni], acc[mi][ni], 0, 0, 0);
    }
    __syncthreads();
  }

  // epilogue: C tile -> LDS + global, then per-head alpha dot
  #pragma unroll
  for (int mi = 0; mi < 4; mi++){
    #pragma unroll
    for (int ni = 0; ni < 4; ni++){
      int col = wc0 + ni * 16 + (lane & 15);
      int rb = mi * 16 + (lane >> 4) * 4;
      #pragma unroll
      for (int r = 0; r < 4; r++){
        int row = rb + r;
        unsigned short us = f2b(acc[mi][ni][r]);
        sC[row][col] = us;
        if (bm0 + row < M) C[(size_t)(bm0 + row) * HID + col] = us;
      }
    }
  }
  __syncthreads();
  {
    int q = wave, r = lane;
    float ps = 0.f, pd = 0.f;
    #pragma unroll 8
    for (int d = 0; d < 64; d++){
      float hv = b2f(sC[r][q * 64 + d]);
      ps += hv * a_src[q * 64 + d];
      pd += hv * a_dst[q * 64 + d];
    }
    if (bm0 + r < M){
      as_[(size_t)(bm0 + r) * 4 + q] = ps;
      ad_[(size_t)(bm0 + r) * 4 + q] = pd;
    }
  }
}

// ---------------- softmax aggregation: 2-deep pipelined single pass ----------------
// One wave per dst node. No online max: logits clamped to +-60 (softmax is
// shift-invariant; data-scale makes |logit| << 60; exp cannot overflow f32).
__global__ __launch_bounds__(256) void k_aggregate(const int* __restrict__ off,
    const int* __restrict__ ssrc, const float* __restrict__ as_, const float* __restrict__ ad_,
    const unsigned short* __restrict__ h, const float* __restrict__ bias,
    unsigned short* __restrict__ out){
  int gid = blockIdx.x * 256 + threadIdx.x;
  int wid = gid >> 6, lane = gid & 63;
  if (wid >= NN) return;
  int start = off[wid], end = off[wid + 1];       // deg >= 1 (self loop)
  int h2 = lane >> 4;
  float ad2 = ad_[(size_t)wid * 4 + h2];
  float ssum = 0.f, a0 = 0.f, a1 = 0.f, a2 = 0.f, a3 = 0.f;

  int sA_ = ssrc[start];
  int sB_ = (start + 1 < end) ? ssrc[start + 1] : sA_;
  float asP = as_[(size_t)sA_ * 4 + h2];
  s16x4 hvP = *(const s16x4*)(h + (size_t)sA_ * HID + lane * 4);

  for (int p = start; p < end; p++){
    // prefetch: ssrc for p+2, as_/h for p+1 (addresses ready from last iter)
    int sC_ = (p + 2 < end) ? ssrc[p + 2] : sB_;
    float asN = as_[(size_t)sB_ * 4 + h2];
    s16x4 hvN = *(const s16x4*)(h + (size_t)sB_ * HID + lane * 4);
    // compute current
    float lg = asP + ad2;
    lg = lg > 0.f ? lg : 0.2f * lg;               // leaky_relu(0.2)
    lg = fminf(fmaxf(lg, -60.f), 60.f);
    float w = __expf(lg);
    ssum += w;
    a0 += w * b2f((unsigned short)hvP[0]);
    a1 += w * b2f((unsigned short)hvP[1]);
    a2 += w * b2f((unsigned short)hvP[2]);
    a3 += w * b2f((unsigned short)hvP[3]);
    // rotate pipeline
    sB_ = sC_; asP = asN; hvP = hvN;
  }
  float inv = 1.f / (ssum + 1e-16f);
  float4 bv = *(const float4*)(bias + lane * 4);
  float o_[4] = {a0 * inv + bv.x, a1 * inv + bv.y, a2 * inv + bv.z, a3 * inv + bv.w};
  size_t ob = (size_t)wid * HID + lane * 4;
  #pragma unroll
  for (int j = 0; j < 4; j++){
    float v = o_[j];
    v = v > 0.f ? v : (__expf(v) - 1.f);          // elu
    out[ob + j] = f2b(v);
  }
}

// ---------------- mean pool + head ----------------
__global__ void k_pool(const unsigned short* __restrict__ X, float* __restrict__ pool){
  int c = threadIdx.x;             // 256
  float acc = 0.f;
  for (int n = blockIdx.x; n < NN; n += gridDim.x) acc += b2f(X[(size_t)n * HID + c]);
  atomicAdd(&pool[c], acc);
}

__global__ void k_head(const float* __restrict__ pool, const float* __restrict__ hW,
                       const float* __restrict__ hb, float* __restrict__ outp){
  int o = threadIdx.x;             // 128
  float acc = hb[o];
  const float invN = 1.f / (float)NN;
  for (int c = 0; c < HID; c++) acc += pool[c] * invN * hW[c * OUTC + o];
  outp[o] = acc;
}

extern "C" void kernel_launch(void* const* d_in, const int* in_sizes, int n_in,
                              void* d_out, int out_size, void* d_ws, size_t ws_size,
                              hipStream_t stream){
  const float* x  = (const float*)d_in[0];
  const int* ei   = (const int*)d_in[1];
  const float* W[3]   = {(const float*)d_in[2],  (const float*)d_in[6],  (const float*)d_in[10]};
  const float* Asr[3] = {(const float*)d_in[3],  (const float*)d_in[7],  (const float*)d_in[11]};
  const float* Adt[3] = {(const float*)d_in[4],  (const float*)d_in[8],  (const float*)d_in[12]};
  const float* B[3]   = {(const float*)d_in[5],  (const float*)d_in[9],  (const float*)d_in[13]};
  const float* hW = (const float*)d_in[14];
  const float* hb = (const float*)d_in[15];

  char* w = (char*)d_ws; size_t o = 0;
  auto alloc = [&](size_t b) -> void* { void* p = w + o; o = (o + b + 255) & ~(size_t)255; return p; };
  int* cnt  = (int*)alloc((size_t)NN * 4);
  int* off  = (int*)alloc((size_t)(NN + 1) * 4);
  int* ssrc = (int*)alloc((size_t)ET * 4);
  unsigned short* hbuf = (unsigned short*)alloc((size_t)NN * HID * 2);
  float* as_ = (float*)alloc((size_t)NN * 4 * 4);
  float* ad_ = (float*)alloc((size_t)NN * 4 * 4);
  unsigned short* X0 = (unsigned short*)alloc((size_t)NN * HID * 2);
  unsigned short* X1 = (unsigned short*)alloc((size_t)NN * HID * 2);
  unsigned short* WT = (unsigned short*)alloc((size_t)256 * 256 * 2);
  float* pool = (float*)alloc(256 * 4);

  hipMemsetAsync(cnt, 0, (size_t)NN * 4, stream);
  hipMemsetAsync(pool, 0, 256 * 4, stream);
  k_degree<<<(ET + 255) / 256, 256, 0, stream>>>(ei, cnt);
  k_scan<<<1, 1024, 0, stream>>>(cnt, off);
  hipMemsetAsync(cnt, 0, (size_t)NN * 4, stream);
  k_scatter<<<(ET + 255) / 256, 256, 0, stream>>>(ei, off, cnt, ssrc);

  unsigned short* outbuf[3] = {X0, X1, X0};
  int Ks[3] = {INC, HID, HID};
  const void* Ain = (const void*)x;
  int gB = (NN + 63) / 64;
  for (int l = 0; l < 3; l++){
    int K = Ks[l];
    k_transpose<<<(K * HID + 255) / 256, 256, 0, stream>>>(W[l], WT, K);
    if (l == 0) k_gemm_fused<true ><<<gB, 256, 0, stream>>>(Ain, WT, Asr[l], Adt[l], hbuf, as_, ad_, NN, K);
    else        k_gemm_fused<false><<<gB, 256, 0, stream>>>(Ain, WT, Asr[l], Adt[l], hbuf, as_, ad_, NN, K);
    k_aggregate<<<(NN * 64 + 255) / 256, 256, 0, stream>>>(off, ssrc, as_, ad_, hbuf, B[l], outbuf[l]);
    Ain = (const void*)outbuf[l];
  }
  k_pool<<<256, 256, 0, stream>>>(X0, pool);
  k_head<<<1, 128, 0, stream>>>(pool, hW, hb, (float*)d_out);
}

// Round 5
// 460.810 us; speedup vs baseline: 1.4563x; 1.2160x over previous
//
#include <hip/hip_runtime.h>
#include <stdint.h>

#define NN 50000
#define EE 800000
#define ET 850000
#define INC 128
#define HID 256
#define OUTC 128
#define NB ((NN + 255) / 256)   // 196 scan blocks

typedef __attribute__((ext_vector_type(4))) float f32x4;
typedef __attribute__((ext_vector_type(8))) short s16x8;
typedef __attribute__((ext_vector_type(4))) short s16x4;

static __device__ __forceinline__ float b2f(unsigned short u){
  union { float f; unsigned int i; } v; v.i = ((unsigned int)u) << 16; return v.f;
}
static __device__ __forceinline__ unsigned short f2b(float f){
  union { float f; unsigned int i; } v; v.f = f;
  unsigned int r = v.i + 0x7FFFu + ((v.i >> 16) & 1u);
  return (unsigned short)(r >> 16);
}

// ---------------- CSR build ----------------
__global__ void k_degree(const int* __restrict__ ei, int* __restrict__ cnt){
  int e = blockIdx.x * 256 + threadIdx.x;
  if (e >= ET) return;
  int d = (e < EE) ? ei[EE + e] : (e - EE);
  atomicAdd(&cnt[d], 1);
}

// hierarchical scan: per-block exclusive scan + block sums
__global__ void k_blockscan(const int* __restrict__ deg, int* __restrict__ off,
                            int* __restrict__ bsum){
  __shared__ int s[256];
  int b = blockIdx.x, tid = threadIdx.x;
  int i = b * 256 + tid;
  int v = (i < NN) ? deg[i] : 0;
  s[tid] = v; __syncthreads();
  #pragma unroll
  for (int o = 1; o < 256; o <<= 1){
    int t = (tid >= o) ? s[tid - o] : 0; __syncthreads();
    s[tid] += t; __syncthreads();
  }
  if (i < NN) off[i] = s[tid] - v;
  if (tid == 255) bsum[b] = s[255];
}

__global__ void k_scanb(const int* __restrict__ bsum, int* __restrict__ bbase){
  __shared__ int s[256];
  int tid = threadIdx.x;
  int v = (tid < NB) ? bsum[tid] : 0;
  s[tid] = v; __syncthreads();
  #pragma unroll
  for (int o = 1; o < 256; o <<= 1){
    int t = (tid >= o) ? s[tid - o] : 0; __syncthreads();
    s[tid] += t; __syncthreads();
  }
  if (tid < NB) bbase[tid] = s[tid] - v;
}

__global__ void k_addback(int* __restrict__ off, const int* __restrict__ bbase){
  int b = blockIdx.x, tid = threadIdx.x;
  int i = b * 256 + tid;
  if (i < NN) off[i] += bbase[b];
  if (i == 0) off[NN] = ET;      // total degree == edge count, known statically
}

__global__ void k_scatter(const int* __restrict__ ei, const int* __restrict__ off,
                          int* __restrict__ cnt, int* __restrict__ ssrc){
  int e = blockIdx.x * 256 + threadIdx.x;
  if (e >= ET) return;
  int s, d;
  if (e < EE){ s = ei[e]; d = ei[EE + e]; } else { s = e - EE; d = s; }
  int p = off[d] + atomicAdd(&cnt[d], 1);
  ssrc[p] = s;
}

// ---------------- W transpose + f32->bf16 (tiny) ----------------
__global__ void k_transpose(const float* __restrict__ W,
                            unsigned short* __restrict__ WT, int K){
  int idx = blockIdx.x * 256 + threadIdx.x;
  if (idx >= K * HID) return;
  int k = idx >> 8, c = idx & 255;
  WT[c * K + k] = f2b(W[idx]);
}

// ---------------- fused MFMA GEMM (64 x 256 tile) + alpha epilogue ----------------
template<bool AF32>
__global__ __launch_bounds__(256) void k_gemm_fused(const void* __restrict__ Av,
    const unsigned short* __restrict__ WT,
    const float* __restrict__ a_src, const float* __restrict__ a_dst,
    unsigned short* __restrict__ C, float* __restrict__ as_, float* __restrict__ ad_,
    int M, int K){
  __shared__ unsigned short sMem[64 * 258];              // 33024 B
  unsigned short (*sA)[72]  = (unsigned short (*)[72])sMem;
  unsigned short (*sC)[258] = (unsigned short (*)[258])sMem;
  int tid = threadIdx.x;
  int wave = tid >> 6, lane = tid & 63;
  int bm0 = blockIdx.x * 64;
  int wc0 = wave * 64;
  f32x4 acc[4][4];
  #pragma unroll
  for (int i = 0; i < 4; i++)
    #pragma unroll
    for (int j = 0; j < 4; j++) acc[i][j] = (f32x4){0.f, 0.f, 0.f, 0.f};

  for (int k0 = 0; k0 < K; k0 += 64){
    #pragma unroll
    for (int i = 0; i < 2; i++){
      int idx = tid + i * 256;
      int r = idx >> 3, kb = (idx & 7) * 8;
      int gr = bm0 + r;
      if constexpr (AF32){
        const float* A = (const float*)Av;
        unsigned short t[8] = {0,0,0,0,0,0,0,0};
        if (gr < M){
          const float4* p = (const float4*)(A + (size_t)gr * K + k0 + kb);
          float4 v0 = p[0], v1 = p[1];
          t[0]=f2b(v0.x); t[1]=f2b(v0.y); t[2]=f2b(v0.z); t[3]=f2b(v0.w);
          t[4]=f2b(v1.x); t[5]=f2b(v1.y); t[6]=f2b(v1.z); t[7]=f2b(v1.w);
        }
        *(s16x8*)&sA[r][kb] = *(s16x8*)t;
      } else {
        const unsigned short* A = (const unsigned short*)Av;
        s16x8 v = (s16x8){0,0,0,0,0,0,0,0};
        if (gr < M) v = *(const s16x8*)(A + (size_t)gr * K + k0 + kb);
        *(s16x8*)&sA[r][kb] = v;
      }
    }
    __syncthreads();
    #pragma unroll
    for (int kk = 0; kk < 64; kk += 32){
      int kl = kk + (lane >> 4) * 8;
      s16x8 af[4], bf[4];
      #pragma unroll
      for (int ni = 0; ni < 4; ni++)
        bf[ni] = *(const s16x8*)(WT + (size_t)(wc0 + ni * 16 + (lane & 15)) * K + k0 + kl);
      #pragma unroll
      for (int mi = 0; mi < 4; mi++) af[mi] = *(const s16x8*)&sA[mi * 16 + (lane & 15)][kl];
      #pragma unroll
      for (int mi = 0; mi < 4; mi++)
        #pragma unroll
        for (int ni = 0; ni < 4; ni++)
          acc[mi][ni] = __builtin_amdgcn_mfma_f32_16x16x32_bf16(af[mi], bf[ni], acc[mi][ni], 0, 0, 0);
    }
    __syncthreads();
  }

  #pragma unroll
  for (int mi = 0; mi < 4; mi++){
    #pragma unroll
    for (int ni = 0; ni < 4; ni++){
      int col = wc0 + ni * 16 + (lane & 15);
      int rb = mi * 16 + (lane >> 4) * 4;
      #pragma unroll
      for (int r = 0; r < 4; r++){
        int row = rb + r;
        unsigned short us = f2b(acc[mi][ni][r]);
        sC[row][col] = us;
        if (bm0 + row < M) C[(size_t)(bm0 + row) * HID + col] = us;
      }
    }
  }
  __syncthreads();
  {
    int q = wave, r = lane;
    float ps = 0.f, pd = 0.f;
    #pragma unroll 8
    for (int d = 0; d < 64; d++){
      float hv = b2f(sC[r][q * 64 + d]);
      ps += hv * a_src[q * 64 + d];
      pd += hv * a_dst[q * 64 + d];
    }
    if (bm0 + r < M){
      as_[(size_t)(bm0 + r) * 4 + q] = ps;
      ad_[(size_t)(bm0 + r) * 4 + q] = pd;
    }
  }
}

// ---------------- softmax aggregation: 2-edge unroll, 4-deep pipeline ----------------
// One wave per dst node. No online max (logits O(1); clamp upper at 60 — softmax
// shift-invariance makes this exact in-range, exp underflow at the bottom is safe).
__global__ __launch_bounds__(256) void k_aggregate(const int* __restrict__ off,
    const int* __restrict__ ssrc, const float* __restrict__ as_, const float* __restrict__ ad_,
    const unsigned short* __restrict__ h, const float* __restrict__ bias,
    unsigned short* __restrict__ out){
  int gid = blockIdx.x * 256 + threadIdx.x;
  int wid = gid >> 6, lane = gid & 63;
  if (wid >= NN) return;
  int start = off[wid], end = off[wid + 1];       // deg >= 1 (self loop)
  int hq = lane >> 4;
  float ad2 = ad_[(size_t)wid * 4 + hq];

  float sA = 0.f, sB = 0.f;
  float A0 = 0.f, A1 = 0.f, A2 = 0.f, A3 = 0.f;
  float B0 = 0.f, B1 = 0.f, B2 = 0.f, B3 = 0.f;

  int p = start;
  int i0 = ssrc[p];
  int i1 = (p + 1 < end) ? ssrc[p + 1] : 0;
  int i2 = (p + 2 < end) ? ssrc[p + 2] : 0;
  int i3 = (p + 3 < end) ? ssrc[p + 3] : 0;
  float a0v = as_[(size_t)i0 * 4 + hq], a1v = 0.f;
  s16x4 hv0 = *(const s16x4*)(h + (size_t)i0 * HID + lane * 4);
  s16x4 hv1 = (s16x4){0,0,0,0};
  if (p + 1 < end){
    a1v = as_[(size_t)i1 * 4 + hq];
    hv1 = *(const s16x4*)(h + (size_t)i1 * HID + lane * 4);
  }

  for (; p + 1 < end; p += 2){
    // prefetch values for edges p+2, p+3 and indices for p+4, p+5
    float a2v = 0.f, a3v = 0.f;
    s16x4 hv2 = (s16x4){0,0,0,0}, hv3 = (s16x4){0,0,0,0};
    if (p + 2 < end){ a2v = as_[(size_t)i2 * 4 + hq]; hv2 = *(const s16x4*)(h + (size_t)i2 * HID + lane * 4); }
    if (p + 3 < end){ a3v = as_[(size_t)i3 * 4 + hq]; hv3 = *(const s16x4*)(h + (size_t)i3 * HID + lane * 4); }
    int i4 = (p + 4 < end) ? ssrc[p + 4] : 0;
    int i5 = (p + 5 < end) ? ssrc[p + 5] : 0;
    // compute edges p and p+1
    float lg0 = a0v + ad2; lg0 = lg0 > 0.f ? lg0 : 0.2f * lg0;
    float lg1 = a1v + ad2; lg1 = lg1 > 0.f ? lg1 : 0.2f * lg1;
    float w0 = __expf(fminf(lg0, 60.f));
    float w1 = __expf(fminf(lg1, 60.f));
    sA += w0; sB += w1;
    A0 += w0 * b2f((unsigned short)hv0[0]); B0 += w1 * b2f((unsigned short)hv1[0]);
    A1 += w0 * b2f((unsigned short)hv0[1]); B1 += w1 * b2f((unsigned short)hv1[1]);
    A2 += w0 * b2f((unsigned short)hv0[2]); B2 += w1 * b2f((unsigned short)hv1[2]);
    A3 += w0 * b2f((unsigned short)hv0[3]); B3 += w1 * b2f((unsigned short)hv1[3]);
    i0 = i2; i1 = i3; i2 = i4; i3 = i5;
    a0v = a2v; a1v = a3v; hv0 = hv2; hv1 = hv3;
  }
  if (p < end){                                    // odd tail
    float lg0 = a0v + ad2; lg0 = lg0 > 0.f ? lg0 : 0.2f * lg0;
    float w0 = __expf(fminf(lg0, 60.f));
    sA += w0;
    A0 += w0 * b2f((unsigned short)hv0[0]);
    A1 += w0 * b2f((unsigned short)hv0[1]);
    A2 += w0 * b2f((unsigned short)hv0[2]);
    A3 += w0 * b2f((unsigned short)hv0[3]);
  }
  float inv = 1.f / (sA + sB + 1e-16f);
  float4 bv = *(const float4*)(bias + lane * 4);
  float o_[4] = {(A0 + B0) * inv + bv.x, (A1 + B1) * inv + bv.y,
                 (A2 + B2) * inv + bv.z, (A3 + B3) * inv + bv.w};
  size_t ob = (size_t)wid * HID + lane * 4;
  #pragma unroll
  for (int j = 0; j < 4; j++){
    float v = o_[j];
    v = v > 0.f ? v : (__expf(v) - 1.f);          // elu
    out[ob + j] = f2b(v);
  }
}

// ---------------- mean pool + head ----------------
__global__ void k_pool(const unsigned short* __restrict__ X, float* __restrict__ pool){
  int c = threadIdx.x;             // 256
  float acc = 0.f;
  for (int n = blockIdx.x; n < NN; n += gridDim.x) acc += b2f(X[(size_t)n * HID + c]);
  atomicAdd(&pool[c], acc);
}

__global__ void k_head(const float* __restrict__ pool, const float* __restrict__ hW,
                       const float* __restrict__ hb, float* __restrict__ outp){
  int o = threadIdx.x;             // 128
  float acc = hb[o];
  const float invN = 1.f / (float)NN;
  for (int c = 0; c < HID; c++) acc += pool[c] * invN * hW[c * OUTC + o];
  outp[o] = acc;
}

extern "C" void kernel_launch(void* const* d_in, const int* in_sizes, int n_in,
                              void* d_out, int out_size, void* d_ws, size_t ws_size,
                              hipStream_t stream){
  const float* x  = (const float*)d_in[0];
  const int* ei   = (const int*)d_in[1];
  const float* W[3]   = {(const float*)d_in[2],  (const float*)d_in[6],  (const float*)d_in[10]};
  const float* Asr[3] = {(const float*)d_in[3],  (const float*)d_in[7],  (const float*)d_in[11]};
  const float* Adt[3] = {(const float*)d_in[4],  (const float*)d_in[8],  (const float*)d_in[12]};
  const float* B[3]   = {(const float*)d_in[5],  (const float*)d_in[9],  (const float*)d_in[13]};
  const float* hW = (const float*)d_in[14];
  const float* hb = (const float*)d_in[15];

  char* w = (char*)d_ws; size_t o = 0;
  auto alloc = [&](size_t b) -> void* { void* p = w + o; o = (o + b + 255) & ~(size_t)255; return p; };
  int* cnt  = (int*)alloc((size_t)NN * 4);
  int* off  = (int*)alloc((size_t)(NN + 1) * 4);
  int* ssrc = (int*)alloc((size_t)ET * 4);
  int* bsum = (int*)alloc((size_t)NB * 4);
  int* bbase= (int*)alloc((size_t)NB * 4);
  unsigned short* hbuf = (unsigned short*)alloc((size_t)NN * HID * 2);
  float* as_ = (float*)alloc((size_t)NN * 4 * 4);
  float* ad_ = (float*)alloc((size_t)NN * 4 * 4);
  unsigned short* X0 = (unsigned short*)alloc((size_t)NN * HID * 2);
  unsigned short* X1 = (unsigned short*)alloc((size_t)NN * HID * 2);
  unsigned short* WT = (unsigned short*)alloc((size_t)256 * 256 * 2);
  float* pool = (float*)alloc(256 * 4);

  hipMemsetAsync(cnt, 0, (size_t)NN * 4, stream);
  hipMemsetAsync(pool, 0, 256 * 4, stream);
  k_degree<<<(ET + 255) / 256, 256, 0, stream>>>(ei, cnt);
  k_blockscan<<<NB, 256, 0, stream>>>(cnt, off, bsum);
  k_scanb<<<1, 256, 0, stream>>>(bsum, bbase);
  k_addback<<<NB, 256, 0, stream>>>(off, bbase);
  hipMemsetAsync(cnt, 0, (size_t)NN * 4, stream);
  k_scatter<<<(ET + 255) / 256, 256, 0, stream>>>(ei, off, cnt, ssrc);

  unsigned short* outbuf[3] = {X0, X1, X0};
  int Ks[3] = {INC, HID, HID};
  const void* Ain = (const void*)x;
  int gB = (NN + 63) / 64;
  for (int l = 0; l < 3; l++){
    int K = Ks[l];
    k_transpose<<<(K * HID + 255) / 256, 256, 0, stream>>>(W[l], WT, K);
    if (l == 0) k_gemm_fused<true ><<<gB, 256, 0, stream>>>(Ain, WT, Asr[l], Adt[l], hbuf, as_, ad_, NN, K);
    else        k_gemm_fused<false><<<gB, 256, 0, stream>>>(Ain, WT, Asr[l], Adt[l], hbuf, as_, ad_, NN, K);
    k_aggregate<<<(NN * 64 + 255) / 256, 256, 0, stream>>>(off, ssrc, as_, ad_, hbuf, B[l], outbuf[l]);
    Ain = (const void*)outbuf[l];
  }
  k_pool<<<256, 256, 0, stream>>>(X0, pool);
  k_head<<<1, 128, 0, stream>>>(pool, hW, hb, (float*)d_out);
}